// Round 6
// baseline (554.481 us; speedup 1.0000x reference)
//
#include <hip/hip_runtime.h>
#include <math.h>

#define IN_C   128
#define OUT_C  64
#define EDIM   16
#define EHID   32
#define GN_EPS 1e-5f

typedef unsigned long long u64;

__device__ __forceinline__ float dot4(float4 a, float4 b) {
    return a.x * b.x + a.y * b.y + a.z * b.z + a.w * b.w;
}
__device__ __forceinline__ void fma4(float4& a, float s, float4 w) {
    a.x = fmaf(s, w.x, a.x); a.y = fmaf(s, w.y, a.y);
    a.z = fmaf(s, w.z, a.z); a.w = fmaf(s, w.w, a.w);
}
__device__ __forceinline__ float getc(float4 v, int j) {
    return j == 0 ? v.x : j == 1 ? v.y : j == 2 ? v.z : v.w;
}

// ---------------------------------------------------------------------------
// K0: init  degcnt = {cnt:0, deg:1.0 fixed-point} (self-loop), sums = 0
// ---------------------------------------------------------------------------
__global__ void k_init(u64* __restrict__ degcnt, float* __restrict__ sums, int N) {
    int i = blockIdx.x * 256 + threadIdx.x;
    if (i < N) degcnt[i] = (1ull << 32);          // deg = 1.0 in 2^32 fixed point
    if (i < 2 * OUT_C) sums[i] = 0.f;
}

// ---------------------------------------------------------------------------
// K1a: edge MLP ONLY (no atomics). R5 proved the MLP implementation is NOT
// k_edge's critical path (LDS vs scalar-pipe identical 105us; atomic wait
// dominates). Split out so (1) the MLP runs at its own speed, (2) k_count
// measures the atomic floor in isolation. Scalar-pipe weights (R5-proven:
// wave-uniform indices -> s_load, 0 LDS). 2 edges/thread.
// ---------------------------------------------------------------------------
__global__ void k_mlp(const float* __restrict__ ea,
                      const float* __restrict__ w1, const float* __restrict__ b1,
                      const float* __restrict__ w2, const float* __restrict__ b2,
                      float* __restrict__ ewbuf, int E) {
    int e0 = blockIdx.x * 512 + threadIdx.x;
    int e1 = e0 + 256;
    bool v0 = e0 < E, v1 = e1 < E;
    int e0c = min(e0, E - 1), e1c = min(e1, E - 1);

    const float4* p0 = (const float4*)ea + (size_t)e0c * 4;
    const float4* p1 = (const float4*)ea + (size_t)e1c * 4;
    float4 A0 = p0[0], A1 = p0[1], A2 = p0[2], A3 = p0[3];
    float4 B0 = p1[0], B1 = p1[1], B2 = p1[2], B3 = p1[3];

    const float4* w1v = (const float4*)w1;    // uniform -> scalar loads
    float z0 = b2[0], z1 = z0;
    #pragma unroll
    for (int j = 0; j < EHID; ++j) {
        float4 q0 = w1v[j * 4 + 0];
        float4 q1 = w1v[j * 4 + 1];
        float4 q2 = w1v[j * 4 + 2];
        float4 q3 = w1v[j * 4 + 3];
        float bj = b1[j], wj = w2[j];
        float h0 = dot4(A0, q0) + dot4(A1, q1) + dot4(A2, q2) + dot4(A3, q3) + bj;
        float h1 = dot4(B0, q0) + dot4(B1, q1) + dot4(B2, q2) + dot4(B3, q3) + bj;
        z0 += fmaxf(h0, 0.f) * wj;
        z1 += fmaxf(h1, 0.f) * wj;
    }
    if (v0) ewbuf[e0] = 1.f / (1.f + __expf(-z0));
    if (v1) ewbuf[e1] = 1.f / (1.f + __expf(-z1));
}

// ---------------------------------------------------------------------------
// K1b: counting pass — ONE u64 RMW-with-return per thread (R0-proven idiom:
// u64, 1/thread; R1 u32+paired and R2 4/thread both stormed ~20x traffic).
// This kernel's duration IS the measured atomic floor.
// tmp[e] = {row | rank<<17, ew}
// ---------------------------------------------------------------------------
__global__ void k_count(const int* __restrict__ ei, const float* __restrict__ ewbuf,
                        u64* __restrict__ degcnt, int2* __restrict__ tmp, int E) {
    int e = blockIdx.x * 256 + threadIdx.x;
    if (e >= E) return;
    int row = ei[e];
    int col = ei[E + e];
    float ewv = ewbuf[e];
    u64 inc = (1ull << 44) | (u64)(ewv * 4294967296.0f);   // {cnt+=1, deg+=ew}
    u64 old = atomicAdd(&degcnt[col], inc);
    int rank = (int)(old >> 44);                            // edges before this one
    tmp[e] = make_int2(row | (rank << 17), __float_as_int(ewv));
}

// ---------------------------------------------------------------------------
// K2 (fallback path only): unpack degcnt -> dinv and cnt
// ---------------------------------------------------------------------------
__global__ void k_finish(const u64* __restrict__ degcnt, float* __restrict__ dinv,
                         int* __restrict__ cnt, int N) {
    int i = blockIdx.x * 256 + threadIdx.x;
    if (i < N) {
        u64 v = degcnt[i];
        float deg = (float)(v & ((1ull << 44) - 1)) * (1.f / 4294967296.f);
        dinv[i] = rsqrtf(deg);                    // deg >= 1 always
        cnt[i] = (int)(v >> 44);
    }
}

// ---------------------------------------------------------------------------
// scan1 (CSR path): fused k_finish + block-local exclusive scan of cnt.
// full_start(i) = start[i] + bsums[i>>8]  (scan3 fused into consumers)
// ---------------------------------------------------------------------------
__global__ void k_scan1(const u64* __restrict__ degcnt, int* __restrict__ start,
                        int* __restrict__ bsums, float* __restrict__ dinv,
                        int* __restrict__ cnt, int N) {
    __shared__ int s[256];
    int t = threadIdx.x;
    int i = blockIdx.x * 256 + t;
    int v = 0;
    if (i < N) {
        u64 dv = degcnt[i];
        v = (int)(dv >> 44);
        float deg = (float)(dv & ((1ull << 44) - 1)) * (1.f / 4294967296.f);
        dinv[i] = rsqrtf(deg);
        cnt[i] = v;
    }
    s[t] = v;
    __syncthreads();
    #pragma unroll
    for (int off = 1; off < 256; off <<= 1) {
        int u = (t >= off) ? s[t - off] : 0;
        __syncthreads();
        s[t] += u;
        __syncthreads();
    }
    if (i < N) start[i] = s[t] - v;
    if (t == 255) bsums[blockIdx.x] = s[255];
}
__global__ void k_scan2(int* __restrict__ bsums, int nb) {
    __shared__ int s[1024];
    int t = threadIdx.x;
    s[t] = (t < nb) ? bsums[t] : 0;
    __syncthreads();
    #pragma unroll
    for (int off = 1; off < 1024; off <<= 1) {
        int u = (t >= off) ? s[t - off] : 0;
        __syncthreads();
        s[t] += u;
        __syncthreads();
    }
    if (t < nb) bsums[t] = (t == 0) ? 0 : s[t - 1];
}

// ---------------------------------------------------------------------------
// pass2: atomic-free permute — rec[full_start[col]+rank] = {row, ew}
// ---------------------------------------------------------------------------
__global__ void k_pass2(const int* __restrict__ ei, const int2* __restrict__ tmp,
                        const int* __restrict__ start, const int* __restrict__ bsums,
                        int2* __restrict__ rec, int E) {
    int e = blockIdx.x * 256 + threadIdx.x;
    if (e >= E) return;
    int col = ei[E + e];
    int2 t = tmp[e];
    int rank = ((unsigned)t.x) >> 17;
    int pos = start[col] + bsums[col >> 8] + rank;
    rec[pos] = make_int2(t.x & 0x1FFFF, t.y);
}

// ---------------------------------------------------------------------------
// K3: xts = dinv * (x @ lin_w^T)  — register-tiled 4 rows x 4 ch/lane
// ---------------------------------------------------------------------------
__global__ void k_xt(const float* __restrict__ x, const float* __restrict__ lw,
                     const float* __restrict__ dinv, float* __restrict__ xts, int N) {
    __shared__ float swt[IN_C * OUT_C];
    int tid = threadIdx.x;
    for (int i = tid; i < IN_C * OUT_C; i += 256) {
        int k = i >> 6, c = i & 63;
        swt[i] = lw[c * IN_C + k];
    }
    __syncthreads();

    int lane = tid & 63;
    int c4 = lane & 15;
    int rq = lane >> 4;
    int rbase = blockIdx.x * 64 + (tid >> 6) * 16 + rq * 4;

    int r0 = min(rbase + 0, N - 1), r1 = min(rbase + 1, N - 1);
    int r2 = min(rbase + 2, N - 1), r3 = min(rbase + 3, N - 1);
    const float4* x4 = (const float4*)x;
    float4 acc0 = {0,0,0,0}, acc1 = {0,0,0,0}, acc2 = {0,0,0,0}, acc3 = {0,0,0,0};

    #pragma unroll 4
    for (int k4 = 0; k4 < IN_C / 4; ++k4) {
        float4 xv0 = x4[(size_t)r0 * 32 + k4];
        float4 xv1 = x4[(size_t)r1 * 32 + k4];
        float4 xv2 = x4[(size_t)r2 * 32 + k4];
        float4 xv3 = x4[(size_t)r3 * 32 + k4];
        #pragma unroll
        for (int j = 0; j < 4; ++j) {
            float4 wv = *(const float4*)&swt[(k4 * 4 + j) * OUT_C + (c4 << 2)];
            fma4(acc0, getc(xv0, j), wv);
            fma4(acc1, getc(xv1, j), wv);
            fma4(acc2, getc(xv2, j), wv);
            fma4(acc3, getc(xv3, j), wv);
        }
    }
    int cc = c4 << 2;
    #pragma unroll
    for (int i = 0; i < 4; ++i) {
        int r = rbase + i;
        if (r < N) {
            float d = dinv[r];
            float4 a = i == 0 ? acc0 : i == 1 ? acc1 : i == 2 ? acc2 : acc3;
            a.x *= d; a.y *= d; a.z *= d; a.w *= d;
            *(float4*)&xts[(size_t)r * OUT_C + cc] = a;
        }
    }
}

// ---------------------------------------------------------------------------
// gather: one wave per node, lane = channel; unroll-8.
// out = bias + dinv[node] * (sum_j ew_j * xts[row_j] + xts[node])
// ---------------------------------------------------------------------------
__global__ void k_gather(const int2* __restrict__ rec, const int* __restrict__ start,
                         const int* __restrict__ bsums, const int* __restrict__ cnt,
                         const float* __restrict__ dinv, const float* __restrict__ xts,
                         const float* __restrict__ bias, float* __restrict__ out, int N) {
    int node = blockIdx.x * 4 + (threadIdx.x >> 6);
    if (node >= N) return;
    int lane = threadIdx.x & 63;
    int beg = start[node] + bsums[node >> 8];
    int num = cnt[node];
    float acc = xts[((size_t)node << 6) + lane];      // self-loop term
    int j = 0;
    for (; j + 8 <= num; j += 8) {
        int2 rc[8];
        #pragma unroll
        for (int u = 0; u < 8; ++u) rc[u] = rec[beg + j + u];
        float v[8];
        #pragma unroll
        for (int u = 0; u < 8; ++u) v[u] = xts[((size_t)rc[u].x << 6) + lane];
        #pragma unroll
        for (int u = 0; u < 8; ++u) acc = fmaf(__int_as_float(rc[u].y), v[u], acc);
    }
    for (; j < num; ++j) {
        int2 rc = rec[beg + j];
        acc = fmaf(__int_as_float(rc.y), xts[((size_t)rc.x << 6) + lane], acc);
    }
    out[((size_t)node << 6) + lane] = bias[lane] + dinv[node] * acc;
}

// ---------------------------------------------------------------------------
// fallback (emergency, if ws too small for rec): atomic scatter path
// ---------------------------------------------------------------------------
__global__ void k_init_out(const float* __restrict__ bias, const float* __restrict__ dinv,
                           const float* __restrict__ xts, float* __restrict__ out, int total) {
    int t = blockIdx.x * 256 + threadIdx.x;
    if (t >= total) return;
    int i = t >> 6, c = t & 63;
    out[t] = bias[c] + dinv[i] * xts[t];
}
__global__ void k_scatter(const int* __restrict__ ei, const int2* __restrict__ tmp,
                          const float* __restrict__ dinv, const float* __restrict__ xts,
                          float* __restrict__ out, int E) {
    int t = blockIdx.x * 256 + threadIdx.x;
    int e = t >> 6;
    if (e >= E) return;
    int lane = t & 63;
    int2 tm = tmp[e];
    int row = tm.x & 0x1FFFF;
    int col = ei[E + e];
    float w = dinv[col] * __int_as_float(tm.y);
    atomicAdd(out + (size_t)col * OUT_C + lane, w * xts[(size_t)row * OUT_C + lane]);
}

// ---------------------------------------------------------------------------
// PReLU + GraphNorm stats + apply
// ---------------------------------------------------------------------------
__global__ void k_stats(const float* __restrict__ out, const float* __restrict__ pa,
                        float* __restrict__ sums, int total) {
    __shared__ float r1[256], r2[256];
    float a = pa[0];
    float s = 0.f, s2 = 0.f;
    int stride = gridDim.x * 256;
    for (int t = blockIdx.x * 256 + threadIdx.x; t < total; t += stride) {
        float v = out[t];
        float y = v >= 0.f ? v : a * v;
        s += y; s2 += y * y;
    }
    int tid = threadIdx.x;
    r1[tid] = s; r2[tid] = s2;
    __syncthreads();
    if (tid < 64) {
        float t1 = r1[tid] + r1[tid + 64] + r1[tid + 128] + r1[tid + 192];
        float t2 = r2[tid] + r2[tid + 64] + r2[tid + 128] + r2[tid + 192];
        atomicAdd(&sums[tid], t1);
        atomicAdd(&sums[OUT_C + tid], t2);
    }
}
__global__ void k_apply(float* __restrict__ out, const float* __restrict__ pa,
                        const float* __restrict__ sums,
                        const float* __restrict__ gw, const float* __restrict__ gb,
                        const float* __restrict__ gms, int total, float invN) {
    int t = blockIdx.x * 256 + threadIdx.x;
    if (t >= total) return;
    int c = t & 63;
    float a  = pa[0];
    float m  = sums[c] * invN;
    float ms = gms[c];
    float var = sums[OUT_C + c] * invN - ms * m * m * (2.f - ms);
    float A = gw[c] * rsqrtf(var + GN_EPS);
    float v = out[t];
    float y = v >= 0.f ? v : a * v;
    out[t] = A * (y - ms * m) + gb[c];
}

// ---------------------------------------------------------------------------
extern "C" void kernel_launch(void* const* d_in, const int* in_sizes, int n_in,
                              void* d_out, int out_size, void* d_ws, size_t ws_size,
                              hipStream_t stream) {
    (void)n_in; (void)out_size;
    const float* x    = (const float*)d_in[0];
    const int*   ei   = (const int*)  d_in[1];   // [2,E] row-major int32
    const float* ea   = (const float*)d_in[2];
    const float* lw   = (const float*)d_in[3];
    const float* bias = (const float*)d_in[4];
    const float* w1   = (const float*)d_in[5];
    const float* b1   = (const float*)d_in[6];
    const float* w2   = (const float*)d_in[7];
    const float* b2   = (const float*)d_in[8];
    const float* pa   = (const float*)d_in[9];
    const float* gw   = (const float*)d_in[10];
    const float* gb   = (const float*)d_in[11];
    const float* gms  = (const float*)d_in[12];
    float* out = (float*)d_out;

    int N = in_sizes[0] / IN_C;
    int E = in_sizes[2] / EDIM;
    int total = N * OUT_C;
    int nbN = (N + 255) / 256;
    int nbE = (E + 255) / 256;
    int nbE2 = (E + 511) / 512;

    // workspace layout (degcnt first for 8B alignment; rec LAST for fallback)
    char* p = (char*)d_ws;
    u64*   degcnt = (u64*)p;  p += sizeof(u64) * (size_t)N;
    float* dinv   = (float*)p; p += sizeof(float) * (size_t)N;
    float* xts    = (float*)p; p += sizeof(float) * (size_t)N * OUT_C;
    float* sums   = (float*)p; p += sizeof(float) * 128;
    int*   cnt    = (int*)p;   p += sizeof(int) * (size_t)N;
    int*   startv = (int*)p;   p += sizeof(int) * (size_t)N;
    int*   bsums  = (int*)p;   p += sizeof(int) * 1024;
    float* ewbuf  = (float*)p; p += sizeof(float) * (size_t)E;
    int2*  tmp    = (int2*)p;  p += sizeof(int2) * (size_t)E;
    int2*  rec    = (int2*)p;  p += sizeof(int2) * (size_t)E;
    size_t need = (size_t)(p - (char*)d_ws);
    bool use_csr = (need <= ws_size) && (nbN <= 1024);

    k_init  <<<nbN, 256, 0, stream>>>(degcnt, sums, N);
    k_mlp   <<<nbE2, 256, 0, stream>>>(ea, w1, b1, w2, b2, ewbuf, E);
    k_count <<<nbE, 256, 0, stream>>>(ei, ewbuf, degcnt, tmp, E);

    if (use_csr) {
        k_scan1 <<<nbN, 256, 0, stream>>>(degcnt, startv, bsums, dinv, cnt, N);
        k_scan2 <<<1, 1024, 0, stream>>>(bsums, nbN);
        k_pass2 <<<nbE, 256, 0, stream>>>(ei, tmp, startv, bsums, rec, E);
        k_xt    <<<(N + 63) / 64, 256, 0, stream>>>(x, lw, dinv, xts, N);
        k_gather<<<(N + 3) / 4, 256, 0, stream>>>(rec, startv, bsums, cnt, dinv, xts, bias, out, N);
    } else {
        k_finish<<<nbN, 256, 0, stream>>>(degcnt, dinv, cnt, N);
        k_xt    <<<(N + 63) / 64, 256, 0, stream>>>(x, lw, dinv, xts, N);
        k_init_out<<<(total + 255) / 256, 256, 0, stream>>>(bias, dinv, xts, out, total);
        long st = (long)E * 64;
        k_scatter <<<(unsigned)((st + 255) / 256), 256, 0, stream>>>(ei, tmp, dinv, xts, out, E);
    }

    k_stats <<<512, 256, 0, stream>>>(out, pa, sums, total);
    k_apply <<<(total + 255) / 256, 256, 0, stream>>>(out, pa, sums, gw, gb, gms, total,
                                                      1.0f / (float)N);
}

// Round 7
// 541.174 us; speedup vs baseline: 1.0246x; 1.0246x over previous
//
#include <hip/hip_runtime.h>
#include <math.h>

#define IN_C   128
#define OUT_C  64
#define EDIM   16
#define EHID   32
#define GN_EPS 1e-5f

typedef unsigned long long u64;

__device__ __forceinline__ float dot4(float4 a, float4 b) {
    return a.x * b.x + a.y * b.y + a.z * b.z + a.w * b.w;
}
__device__ __forceinline__ void fma4(float4& a, float s, float4 w) {
    a.x = fmaf(s, w.x, a.x); a.y = fmaf(s, w.y, a.y);
    a.z = fmaf(s, w.z, a.z); a.w = fmaf(s, w.w, a.w);
}
__device__ __forceinline__ float getc(float4 v, int j) {
    return j == 0 ? v.x : j == 1 ? v.y : j == 2 ? v.z : v.w;
}

// ---------------------------------------------------------------------------
// K0: init  degcnt = {cnt:0, deg:1.0 fixed-point} (self-loop), cursor = 0,
// sums = 0
// ---------------------------------------------------------------------------
__global__ void k_init(u64* __restrict__ degcnt, u64* __restrict__ cursor,
                       float* __restrict__ sums, int N) {
    int i = blockIdx.x * 256 + threadIdx.x;
    if (i < N) { degcnt[i] = (1ull << 32); cursor[i] = 0ull; }
    if (i < 2 * OUT_C) sums[i] = 0.f;
}

// ---------------------------------------------------------------------------
// K1: fused edge MLP + FIRE-AND-FORGET degree atomic. R6 measured the
// atomic-with-return floor at ~77us (k_count) and the fused MLP marginal
// cost at ~28us. The rank return is NOT needed here — rank assignment moved
// to pass2 (order was already nondeterministic). Without the return use
// there is no vmcnt wait: kernel is pure MLP (~35us predicted).
// Structure is R5-EXACT (1 edge/thread, scalar-pipe weights): the 2-edge
// interleaved form (R6 k_mlp) triggered a 4-6x VALU codegen pathology, and
// R1/R2 atomic deviations (early issue / 4 per thread) stormed — none of
// that here: same issue rate as R0/R5, u64, post-MLP.
// tmp[e] = {row, ew}   (no rank field anymore)
// ---------------------------------------------------------------------------
__global__ void k_edge(const float* __restrict__ ea, const int* __restrict__ ei,
                       const float* __restrict__ w1, const float* __restrict__ b1,
                       const float* __restrict__ w2, const float* __restrict__ b2,
                       u64* __restrict__ degcnt, int2* __restrict__ tmp, int E) {
    int e = blockIdx.x * 256 + threadIdx.x;
    if (e >= E) return;

    const float4* eav = (const float4*)ea + (size_t)e * 4;
    float4 a0 = eav[0], a1 = eav[1], a2 = eav[2], a3 = eav[3];

    const float4* w1v = (const float4*)w1;    // wave-uniform -> s_load (R5-proven)
    float z = b2[0];
    #pragma unroll
    for (int j = 0; j < EHID; ++j) {
        float4 q0 = w1v[j * 4 + 0];
        float4 q1 = w1v[j * 4 + 1];
        float4 q2 = w1v[j * 4 + 2];
        float4 q3 = w1v[j * 4 + 3];
        float h = dot4(a0, q0) + dot4(a1, q1) + dot4(a2, q2) + dot4(a3, q3) + b1[j];
        h = fmaxf(h, 0.f);
        z += h * w2[j];
    }
    float ewv = 1.f / (1.f + __expf(-z));

    int row = ei[e];
    int col = ei[E + e];
    u64 inc = (1ull << 44) | (u64)(ewv * 4294967296.0f);   // {cnt+=1, deg+=ew}
    atomicAdd(&degcnt[col], inc);                           // no return use: no wait
    tmp[e] = make_int2(row, __float_as_int(ewv));
}

// ---------------------------------------------------------------------------
// K2 (fallback path only): unpack degcnt -> dinv and cnt
// ---------------------------------------------------------------------------
__global__ void k_finish(const u64* __restrict__ degcnt, float* __restrict__ dinv,
                         int* __restrict__ cnt, int N) {
    int i = blockIdx.x * 256 + threadIdx.x;
    if (i < N) {
        u64 v = degcnt[i];
        float deg = (float)(v & ((1ull << 44) - 1)) * (1.f / 4294967296.f);
        dinv[i] = rsqrtf(deg);                    // deg >= 1 always
        cnt[i] = (int)(v >> 44);
    }
}

// ---------------------------------------------------------------------------
// scan1 (CSR path): fused k_finish + block-local exclusive scan of cnt.
// full_start(i) = start[i] + bsums[i>>8]  (scan3 fused into consumers)
// ---------------------------------------------------------------------------
__global__ void k_scan1(const u64* __restrict__ degcnt, int* __restrict__ start,
                        int* __restrict__ bsums, float* __restrict__ dinv,
                        int* __restrict__ cnt, int N) {
    __shared__ int s[256];
    int t = threadIdx.x;
    int i = blockIdx.x * 256 + t;
    int v = 0;
    if (i < N) {
        u64 dv = degcnt[i];
        v = (int)(dv >> 44);
        float deg = (float)(dv & ((1ull << 44) - 1)) * (1.f / 4294967296.f);
        dinv[i] = rsqrtf(deg);
        cnt[i] = v;
    }
    s[t] = v;
    __syncthreads();
    #pragma unroll
    for (int off = 1; off < 256; off <<= 1) {
        int u = (t >= off) ? s[t - off] : 0;
        __syncthreads();
        s[t] += u;
        __syncthreads();
    }
    if (i < N) start[i] = s[t] - v;
    if (t == 255) bsums[blockIdx.x] = s[255];
}
__global__ void k_scan2(int* __restrict__ bsums, int nb) {
    __shared__ int s[1024];
    int t = threadIdx.x;
    s[t] = (t < nb) ? bsums[t] : 0;
    __syncthreads();
    #pragma unroll
    for (int off = 1; off < 1024; off <<= 1) {
        int u = (t >= off) ? s[t - off] : 0;
        __syncthreads();
        s[t] += u;
        __syncthreads();
    }
    if (t < nb) bsums[t] = (t == 0) ? 0 : s[t - 1];
}

// ---------------------------------------------------------------------------
// pass2: permute with rank assignment — rank = atomicAdd(cursor[col], 1).
// This is the k_count-proven atomic pattern (u64, 1/thread, ~77us floor);
// the scattered rec write hides under the atomic wait.
// ---------------------------------------------------------------------------
__global__ void k_pass2(const int* __restrict__ ei, const int2* __restrict__ tmp,
                        const int* __restrict__ start, const int* __restrict__ bsums,
                        u64* __restrict__ cursor, int2* __restrict__ rec, int E) {
    int e = blockIdx.x * 256 + threadIdx.x;
    if (e >= E) return;
    int col = ei[E + e];
    int2 t = tmp[e];
    int rank = (int)atomicAdd(&cursor[col], 1ull);
    int pos = start[col] + bsums[col >> 8] + rank;
    rec[pos] = t;
}

// ---------------------------------------------------------------------------
// K3: xts = dinv * (x @ lin_w^T)  — register-tiled 4 rows x 4 ch/lane
// ---------------------------------------------------------------------------
__global__ void k_xt(const float* __restrict__ x, const float* __restrict__ lw,
                     const float* __restrict__ dinv, float* __restrict__ xts, int N) {
    __shared__ float swt[IN_C * OUT_C];
    int tid = threadIdx.x;
    for (int i = tid; i < IN_C * OUT_C; i += 256) {
        int k = i >> 6, c = i & 63;
        swt[i] = lw[c * IN_C + k];
    }
    __syncthreads();

    int lane = tid & 63;
    int c4 = lane & 15;
    int rq = lane >> 4;
    int rbase = blockIdx.x * 64 + (tid >> 6) * 16 + rq * 4;

    int r0 = min(rbase + 0, N - 1), r1 = min(rbase + 1, N - 1);
    int r2 = min(rbase + 2, N - 1), r3 = min(rbase + 3, N - 1);
    const float4* x4 = (const float4*)x;
    float4 acc0 = {0,0,0,0}, acc1 = {0,0,0,0}, acc2 = {0,0,0,0}, acc3 = {0,0,0,0};

    #pragma unroll 4
    for (int k4 = 0; k4 < IN_C / 4; ++k4) {
        float4 xv0 = x4[(size_t)r0 * 32 + k4];
        float4 xv1 = x4[(size_t)r1 * 32 + k4];
        float4 xv2 = x4[(size_t)r2 * 32 + k4];
        float4 xv3 = x4[(size_t)r3 * 32 + k4];
        #pragma unroll
        for (int j = 0; j < 4; ++j) {
            float4 wv = *(const float4*)&swt[(k4 * 4 + j) * OUT_C + (c4 << 2)];
            fma4(acc0, getc(xv0, j), wv);
            fma4(acc1, getc(xv1, j), wv);
            fma4(acc2, getc(xv2, j), wv);
            fma4(acc3, getc(xv3, j), wv);
        }
    }
    int cc = c4 << 2;
    #pragma unroll
    for (int i = 0; i < 4; ++i) {
        int r = rbase + i;
        if (r < N) {
            float d = dinv[r];
            float4 a = i == 0 ? acc0 : i == 1 ? acc1 : i == 2 ? acc2 : acc3;
            a.x *= d; a.y *= d; a.z *= d; a.w *= d;
            *(float4*)&xts[(size_t)r * OUT_C + cc] = a;
        }
    }
}

// ---------------------------------------------------------------------------
// gather: one wave per node, lane = channel; unroll-8.
// out = bias + dinv[node] * (sum_j ew_j * xts[row_j] + xts[node])
// ---------------------------------------------------------------------------
__global__ void k_gather(const int2* __restrict__ rec, const int* __restrict__ start,
                         const int* __restrict__ bsums, const int* __restrict__ cnt,
                         const float* __restrict__ dinv, const float* __restrict__ xts,
                         const float* __restrict__ bias, float* __restrict__ out, int N) {
    int node = blockIdx.x * 4 + (threadIdx.x >> 6);
    if (node >= N) return;
    int lane = threadIdx.x & 63;
    int beg = start[node] + bsums[node >> 8];
    int num = cnt[node];
    float acc = xts[((size_t)node << 6) + lane];      // self-loop term
    int j = 0;
    for (; j + 8 <= num; j += 8) {
        int2 rc[8];
        #pragma unroll
        for (int u = 0; u < 8; ++u) rc[u] = rec[beg + j + u];
        float v[8];
        #pragma unroll
        for (int u = 0; u < 8; ++u) v[u] = xts[((size_t)rc[u].x << 6) + lane];
        #pragma unroll
        for (int u = 0; u < 8; ++u) acc = fmaf(__int_as_float(rc[u].y), v[u], acc);
    }
    for (; j < num; ++j) {
        int2 rc = rec[beg + j];
        acc = fmaf(__int_as_float(rc.y), xts[((size_t)rc.x << 6) + lane], acc);
    }
    out[((size_t)node << 6) + lane] = bias[lane] + dinv[node] * acc;
}

// ---------------------------------------------------------------------------
// fallback (emergency, if ws too small for rec): atomic scatter path
// ---------------------------------------------------------------------------
__global__ void k_init_out(const float* __restrict__ bias, const float* __restrict__ dinv,
                           const float* __restrict__ xts, float* __restrict__ out, int total) {
    int t = blockIdx.x * 256 + threadIdx.x;
    if (t >= total) return;
    int i = t >> 6, c = t & 63;
    out[t] = bias[c] + dinv[i] * xts[t];
}
__global__ void k_scatter(const int* __restrict__ ei, const int2* __restrict__ tmp,
                          const float* __restrict__ dinv, const float* __restrict__ xts,
                          float* __restrict__ out, int E) {
    int t = blockIdx.x * 256 + threadIdx.x;
    int e = t >> 6;
    if (e >= E) return;
    int lane = t & 63;
    int2 tm = tmp[e];
    int row = tm.x & 0x1FFFF;
    int col = ei[E + e];
    float w = dinv[col] * __int_as_float(tm.y);
    atomicAdd(out + (size_t)col * OUT_C + lane, w * xts[(size_t)row * OUT_C + lane]);
}

// ---------------------------------------------------------------------------
// PReLU + GraphNorm stats + apply
// ---------------------------------------------------------------------------
__global__ void k_stats(const float* __restrict__ out, const float* __restrict__ pa,
                        float* __restrict__ sums, int total) {
    __shared__ float r1[256], r2[256];
    float a = pa[0];
    float s = 0.f, s2 = 0.f;
    int stride = gridDim.x * 256;
    for (int t = blockIdx.x * 256 + threadIdx.x; t < total; t += stride) {
        float v = out[t];
        float y = v >= 0.f ? v : a * v;
        s += y; s2 += y * y;
    }
    int tid = threadIdx.x;
    r1[tid] = s; r2[tid] = s2;
    __syncthreads();
    if (tid < 64) {
        float t1 = r1[tid] + r1[tid + 64] + r1[tid + 128] + r1[tid + 192];
        float t2 = r2[tid] + r2[tid + 64] + r2[tid + 128] + r2[tid + 192];
        atomicAdd(&sums[tid], t1);
        atomicAdd(&sums[OUT_C + tid], t2);
    }
}
__global__ void k_apply(float* __restrict__ out, const float* __restrict__ pa,
                        const float* __restrict__ sums,
                        const float* __restrict__ gw, const float* __restrict__ gb,
                        const float* __restrict__ gms, int total, float invN) {
    int t = blockIdx.x * 256 + threadIdx.x;
    if (t >= total) return;
    int c = t & 63;
    float a  = pa[0];
    float m  = sums[c] * invN;
    float ms = gms[c];
    float var = sums[OUT_C + c] * invN - ms * m * m * (2.f - ms);
    float A = gw[c] * rsqrtf(var + GN_EPS);
    float v = out[t];
    float y = v >= 0.f ? v : a * v;
    out[t] = A * (y - ms * m) + gb[c];
}

// ---------------------------------------------------------------------------
extern "C" void kernel_launch(void* const* d_in, const int* in_sizes, int n_in,
                              void* d_out, int out_size, void* d_ws, size_t ws_size,
                              hipStream_t stream) {
    (void)n_in; (void)out_size;
    const float* x    = (const float*)d_in[0];
    const int*   ei   = (const int*)  d_in[1];   // [2,E] row-major int32
    const float* ea   = (const float*)d_in[2];
    const float* lw   = (const float*)d_in[3];
    const float* bias = (const float*)d_in[4];
    const float* w1   = (const float*)d_in[5];
    const float* b1   = (const float*)d_in[6];
    const float* w2   = (const float*)d_in[7];
    const float* b2   = (const float*)d_in[8];
    const float* pa   = (const float*)d_in[9];
    const float* gw   = (const float*)d_in[10];
    const float* gb   = (const float*)d_in[11];
    const float* gms  = (const float*)d_in[12];
    float* out = (float*)d_out;

    int N = in_sizes[0] / IN_C;
    int E = in_sizes[2] / EDIM;
    int total = N * OUT_C;
    int nbN = (N + 255) / 256;
    int nbE = (E + 255) / 256;

    // workspace layout (u64 arrays first for 8B alignment; rec LAST)
    char* p = (char*)d_ws;
    u64*   degcnt = (u64*)p;  p += sizeof(u64) * (size_t)N;
    u64*   cursor = (u64*)p;  p += sizeof(u64) * (size_t)N;
    float* dinv   = (float*)p; p += sizeof(float) * (size_t)N;
    float* xts    = (float*)p; p += sizeof(float) * (size_t)N * OUT_C;
    float* sums   = (float*)p; p += sizeof(float) * 128;
    int*   cnt    = (int*)p;   p += sizeof(int) * (size_t)N;
    int*   startv = (int*)p;   p += sizeof(int) * (size_t)N;
    int*   bsums  = (int*)p;   p += sizeof(int) * 1024;
    int2*  tmp    = (int2*)p;  p += sizeof(int2) * (size_t)E;
    int2*  rec    = (int2*)p;  p += sizeof(int2) * (size_t)E;
    size_t need = (size_t)(p - (char*)d_ws);
    bool use_csr = (need <= ws_size) && (nbN <= 1024);

    k_init <<<nbN, 256, 0, stream>>>(degcnt, cursor, sums, N);
    k_edge <<<nbE, 256, 0, stream>>>(ea, ei, w1, b1, w2, b2, degcnt, tmp, E);

    if (use_csr) {
        k_scan1 <<<nbN, 256, 0, stream>>>(degcnt, startv, bsums, dinv, cnt, N);
        k_scan2 <<<1, 1024, 0, stream>>>(bsums, nbN);
        k_pass2 <<<nbE, 256, 0, stream>>>(ei, tmp, startv, bsums, cursor, rec, E);
        k_xt    <<<(N + 63) / 64, 256, 0, stream>>>(x, lw, dinv, xts, N);
        k_gather<<<(N + 3) / 4, 256, 0, stream>>>(rec, startv, bsums, cnt, dinv, xts, bias, out, N);
    } else {
        k_finish<<<nbN, 256, 0, stream>>>(degcnt, dinv, cnt, N);
        k_xt    <<<(N + 63) / 64, 256, 0, stream>>>(x, lw, dinv, xts, N);
        k_init_out<<<(total + 255) / 256, 256, 0, stream>>>(bias, dinv, xts, out, total);
        long st = (long)E * 64;
        k_scatter <<<(unsigned)((st + 255) / 256), 256, 0, stream>>>(ei, tmp, dinv, xts, out, E);
    }

    k_stats <<<512, 256, 0, stream>>>(out, pa, sums, total);
    k_apply <<<(total + 255) / 256, 256, 0, stream>>>(out, pa, sums, gw, gb, gms, total,
                                                      1.0f / (float)N);
}

// Round 8
// 458.466 us; speedup vs baseline: 1.2094x; 1.1804x over previous
//
#include <hip/hip_runtime.h>
#include <hip/hip_fp16.h>
#include <math.h>

#define IN_C   128
#define OUT_C  64
#define EDIM   16
#define EHID   32
#define GN_EPS 1e-5f

typedef unsigned long long u64;

__device__ __forceinline__ float dot4(float4 a, float4 b) {
    return a.x * b.x + a.y * b.y + a.z * b.z + a.w * b.w;
}
__device__ __forceinline__ void fma4(float4& a, float s, float4 w) {
    a.x = fmaf(s, w.x, a.x); a.y = fmaf(s, w.y, a.y);
    a.z = fmaf(s, w.z, a.z); a.w = fmaf(s, w.w, a.w);
}
__device__ __forceinline__ float getc(float4 v, int j) {
    return j == 0 ? v.x : j == 1 ? v.y : j == 2 ? v.z : v.w;
}

// ---------------------------------------------------------------------------
// K0: init  degcnt = {cnt:0, deg:1.0 fixed-point} (self-loop), sums = 0
// ---------------------------------------------------------------------------
__global__ void k_init(u64* __restrict__ degcnt, float* __restrict__ sums, int N) {
    int i = blockIdx.x * 256 + threadIdx.x;
    if (i < N) degcnt[i] = (1ull << 32);          // deg = 1.0 in 2^32 fixed point
    if (i < 2 * OUT_C) sums[i] = 0.f;
}

// ---------------------------------------------------------------------------
// K1: fused edge phase — R3-EXACT. MLP (scalar-pipe weights, R5-proven) ->
// ONE u64 RMW-with-return per thread issued AFTER the MLP.
// Atomic ledger: this costs ~100us in ANY placement (R6 k_count 77us pure;
// R7 fire-and-forget still ~95; R7 rank-in-pass2 117) — fusion with the MLP
// is the cheapest home (MLP marginal cost ~28us hides under it). Storms:
// u32 counters (R1) or >1 in-flight atomic/thread (R2) -> 20x traffic.
// u64 + 1/thread is stable. DO NOT DEVIATE.
// tmp[e] = {row | rank<<17, ew}
// ---------------------------------------------------------------------------
__global__ void k_edge(const float* __restrict__ ea, const int* __restrict__ ei,
                       const float* __restrict__ w1, const float* __restrict__ b1,
                       const float* __restrict__ w2, const float* __restrict__ b2,
                       u64* __restrict__ degcnt, int2* __restrict__ tmp, int E) {
    int e = blockIdx.x * 256 + threadIdx.x;
    if (e >= E) return;

    const float4* eav = (const float4*)ea + (size_t)e * 4;
    float4 a0 = eav[0], a1 = eav[1], a2 = eav[2], a3 = eav[3];

    const float4* w1v = (const float4*)w1;    // wave-uniform -> s_load
    float z = b2[0];
    #pragma unroll
    for (int j = 0; j < EHID; ++j) {
        float4 q0 = w1v[j * 4 + 0];
        float4 q1 = w1v[j * 4 + 1];
        float4 q2 = w1v[j * 4 + 2];
        float4 q3 = w1v[j * 4 + 3];
        float h = dot4(a0, q0) + dot4(a1, q1) + dot4(a2, q2) + dot4(a3, q3) + b1[j];
        h = fmaxf(h, 0.f);
        z += h * w2[j];
    }
    float ewv = 1.f / (1.f + __expf(-z));

    int row = ei[e];
    int col = ei[E + e];
    u64 inc = (1ull << 44) | (u64)(ewv * 4294967296.0f);   // {cnt+=1, deg+=ew}
    u64 old = atomicAdd(&degcnt[col], inc);
    int rank = (int)(old >> 44);                            // edges before this one
    tmp[e] = make_int2(row | (rank << 17), __float_as_int(ewv));
}

// ---------------------------------------------------------------------------
// K2 (fallback path only): unpack degcnt -> dinv and cnt
// ---------------------------------------------------------------------------
__global__ void k_finish(const u64* __restrict__ degcnt, float* __restrict__ dinv,
                         int* __restrict__ cnt, int N) {
    int i = blockIdx.x * 256 + threadIdx.x;
    if (i < N) {
        u64 v = degcnt[i];
        float deg = (float)(v & ((1ull << 44) - 1)) * (1.f / 4294967296.f);
        dinv[i] = rsqrtf(deg);                    // deg >= 1 always
        cnt[i] = (int)(v >> 44);
    }
}

// ---------------------------------------------------------------------------
// scan1 (CSR path): fused k_finish + block-local exclusive scan of cnt.
// full_start(i) = start[i] + bsums[i>>8]  (scan3 fused into consumers)
// ---------------------------------------------------------------------------
__global__ void k_scan1(const u64* __restrict__ degcnt, int* __restrict__ start,
                        int* __restrict__ bsums, float* __restrict__ dinv,
                        int* __restrict__ cnt, int N) {
    __shared__ int s[256];
    int t = threadIdx.x;
    int i = blockIdx.x * 256 + t;
    int v = 0;
    if (i < N) {
        u64 dv = degcnt[i];
        v = (int)(dv >> 44);
        float deg = (float)(dv & ((1ull << 44) - 1)) * (1.f / 4294967296.f);
        dinv[i] = rsqrtf(deg);
        cnt[i] = v;
    }
    s[t] = v;
    __syncthreads();
    #pragma unroll
    for (int off = 1; off < 256; off <<= 1) {
        int u = (t >= off) ? s[t - off] : 0;
        __syncthreads();
        s[t] += u;
        __syncthreads();
    }
    if (i < N) start[i] = s[t] - v;
    if (t == 255) bsums[blockIdx.x] = s[255];
}
__global__ void k_scan2(int* __restrict__ bsums, int nb) {
    __shared__ int s[1024];
    int t = threadIdx.x;
    s[t] = (t < nb) ? bsums[t] : 0;
    __syncthreads();
    #pragma unroll
    for (int off = 1; off < 1024; off <<= 1) {
        int u = (t >= off) ? s[t - off] : 0;
        __syncthreads();
        s[t] += u;
        __syncthreads();
    }
    if (t < nb) bsums[t] = (t == 0) ? 0 : s[t - 1];
}

// ---------------------------------------------------------------------------
// pass2: atomic-free permute — rec[full_start[col]+rank] = {row, ew}
// ---------------------------------------------------------------------------
__global__ void k_pass2(const int* __restrict__ ei, const int2* __restrict__ tmp,
                        const int* __restrict__ start, const int* __restrict__ bsums,
                        int2* __restrict__ rec, int E) {
    int e = blockIdx.x * 256 + threadIdx.x;
    if (e >= E) return;
    int col = ei[E + e];
    int2 t = tmp[e];
    int rank = ((unsigned)t.x) >> 17;
    int pos = start[col] + bsums[col >> 8] + rank;
    rec[pos] = make_int2(t.x & 0x1FFFF, t.y);
}

// ---------------------------------------------------------------------------
// K3: xts = dinv * (x @ lin_w^T) stored as FP16 — halves the gather's
// scattered-row traffic (256B -> 128B per edge; ~410 -> ~205 MB), the
// largest byte stream in the pipeline. xts is internal; fp16 adds ~0.01
// abs error over ~17-term sums (current absmax 0.03125 passes).
// ---------------------------------------------------------------------------
__global__ void k_xt(const float* __restrict__ x, const float* __restrict__ lw,
                     const float* __restrict__ dinv, __half* __restrict__ xts, int N) {
    __shared__ float swt[IN_C * OUT_C];
    int tid = threadIdx.x;
    for (int i = tid; i < IN_C * OUT_C; i += 256) {
        int k = i >> 6, c = i & 63;
        swt[i] = lw[c * IN_C + k];
    }
    __syncthreads();

    int lane = tid & 63;
    int c4 = lane & 15;
    int rq = lane >> 4;
    int rbase = blockIdx.x * 64 + (tid >> 6) * 16 + rq * 4;

    int r0 = min(rbase + 0, N - 1), r1 = min(rbase + 1, N - 1);
    int r2 = min(rbase + 2, N - 1), r3 = min(rbase + 3, N - 1);
    const float4* x4 = (const float4*)x;
    float4 acc0 = {0,0,0,0}, acc1 = {0,0,0,0}, acc2 = {0,0,0,0}, acc3 = {0,0,0,0};

    #pragma unroll 4
    for (int k4 = 0; k4 < IN_C / 4; ++k4) {
        float4 xv0 = x4[(size_t)r0 * 32 + k4];
        float4 xv1 = x4[(size_t)r1 * 32 + k4];
        float4 xv2 = x4[(size_t)r2 * 32 + k4];
        float4 xv3 = x4[(size_t)r3 * 32 + k4];
        #pragma unroll
        for (int j = 0; j < 4; ++j) {
            float4 wv = *(const float4*)&swt[(k4 * 4 + j) * OUT_C + (c4 << 2)];
            fma4(acc0, getc(xv0, j), wv);
            fma4(acc1, getc(xv1, j), wv);
            fma4(acc2, getc(xv2, j), wv);
            fma4(acc3, getc(xv3, j), wv);
        }
    }
    int cc = c4 << 2;
    #pragma unroll
    for (int i = 0; i < 4; ++i) {
        int r = rbase + i;
        if (r < N) {
            float d = dinv[r];
            float4 a = i == 0 ? acc0 : i == 1 ? acc1 : i == 2 ? acc2 : acc3;
            union { __half2 h[2]; uint2 u; } cv;
            cv.h[0] = __floats2half2_rn(a.x * d, a.y * d);
            cv.h[1] = __floats2half2_rn(a.z * d, a.w * d);
            *(uint2*)&xts[(size_t)r * OUT_C + cc] = cv.u;
        }
    }
}

// ---------------------------------------------------------------------------
// gather: one wave per node, lane = channel; unroll-8. xts rows are fp16
// (128B/row): 2B/lane coalesced within each row line.
// out = bias + dinv[node] * (sum_j ew_j * xts[row_j] + xts[node])
// ---------------------------------------------------------------------------
__global__ void k_gather(const int2* __restrict__ rec, const int* __restrict__ start,
                         const int* __restrict__ bsums, const int* __restrict__ cnt,
                         const float* __restrict__ dinv, const __half* __restrict__ xts,
                         const float* __restrict__ bias, float* __restrict__ out, int N) {
    int node = blockIdx.x * 4 + (threadIdx.x >> 6);
    if (node >= N) return;
    int lane = threadIdx.x & 63;
    int beg = start[node] + bsums[node >> 8];
    int num = cnt[node];
    float acc = __half2float(xts[((size_t)node << 6) + lane]);   // self-loop term
    int j = 0;
    for (; j + 8 <= num; j += 8) {
        int2 rc[8];
        #pragma unroll
        for (int u = 0; u < 8; ++u) rc[u] = rec[beg + j + u];
        float v[8];
        #pragma unroll
        for (int u = 0; u < 8; ++u) v[u] = __half2float(xts[((size_t)rc[u].x << 6) + lane]);
        #pragma unroll
        for (int u = 0; u < 8; ++u) acc = fmaf(__int_as_float(rc[u].y), v[u], acc);
    }
    for (; j < num; ++j) {
        int2 rc = rec[beg + j];
        acc = fmaf(__int_as_float(rc.y), __half2float(xts[((size_t)rc.x << 6) + lane]), acc);
    }
    out[((size_t)node << 6) + lane] = bias[lane] + dinv[node] * acc;
}

// ---------------------------------------------------------------------------
// fallback (emergency, if ws too small for rec): atomic scatter path
// ---------------------------------------------------------------------------
__global__ void k_init_out(const float* __restrict__ bias, const float* __restrict__ dinv,
                           const __half* __restrict__ xts, float* __restrict__ out, int total) {
    int t = blockIdx.x * 256 + threadIdx.x;
    if (t >= total) return;
    int i = t >> 6, c = t & 63;
    out[t] = bias[c] + dinv[i] * __half2float(xts[t]);
}
__global__ void k_scatter(const int* __restrict__ ei, const int2* __restrict__ tmp,
                          const float* __restrict__ dinv, const __half* __restrict__ xts,
                          float* __restrict__ out, int E) {
    int t = blockIdx.x * 256 + threadIdx.x;
    int e = t >> 6;
    if (e >= E) return;
    int lane = t & 63;
    int2 tm = tmp[e];
    int row = tm.x & 0x1FFFF;
    int col = ei[E + e];
    float w = dinv[col] * __int_as_float(tm.y);
    atomicAdd(out + (size_t)col * OUT_C + lane,
              w * __half2float(xts[(size_t)row * OUT_C + lane]));
}

// ---------------------------------------------------------------------------
// PReLU + GraphNorm stats + apply
// ---------------------------------------------------------------------------
__global__ void k_stats(const float* __restrict__ out, const float* __restrict__ pa,
                        float* __restrict__ sums, int total) {
    __shared__ float r1[256], r2[256];
    float a = pa[0];
    float s = 0.f, s2 = 0.f;
    int stride = gridDim.x * 256;
    for (int t = blockIdx.x * 256 + threadIdx.x; t < total; t += stride) {
        float v = out[t];
        float y = v >= 0.f ? v : a * v;
        s += y; s2 += y * y;
    }
    int tid = threadIdx.x;
    r1[tid] = s; r2[tid] = s2;
    __syncthreads();
    if (tid < 64) {
        float t1 = r1[tid] + r1[tid + 64] + r1[tid + 128] + r1[tid + 192];
        float t2 = r2[tid] + r2[tid + 64] + r2[tid + 128] + r2[tid + 192];
        atomicAdd(&sums[tid], t1);
        atomicAdd(&sums[OUT_C + tid], t2);
    }
}
__global__ void k_apply(float* __restrict__ out, const float* __restrict__ pa,
                        const float* __restrict__ sums,
                        const float* __restrict__ gw, const float* __restrict__ gb,
                        const float* __restrict__ gms, int total, float invN) {
    int t = blockIdx.x * 256 + threadIdx.x;
    if (t >= total) return;
    int c = t & 63;
    float a  = pa[0];
    float m  = sums[c] * invN;
    float ms = gms[c];
    float var = sums[OUT_C + c] * invN - ms * m * m * (2.f - ms);
    float A = gw[c] * rsqrtf(var + GN_EPS);
    float v = out[t];
    float y = v >= 0.f ? v : a * v;
    out[t] = A * (y - ms * m) + gb[c];
}

// ---------------------------------------------------------------------------
extern "C" void kernel_launch(void* const* d_in, const int* in_sizes, int n_in,
                              void* d_out, int out_size, void* d_ws, size_t ws_size,
                              hipStream_t stream) {
    (void)n_in; (void)out_size;
    const float* x    = (const float*)d_in[0];
    const int*   ei   = (const int*)  d_in[1];   // [2,E] row-major int32
    const float* ea   = (const float*)d_in[2];
    const float* lw   = (const float*)d_in[3];
    const float* bias = (const float*)d_in[4];
    const float* w1   = (const float*)d_in[5];
    const float* b1   = (const float*)d_in[6];
    const float* w2   = (const float*)d_in[7];
    const float* b2   = (const float*)d_in[8];
    const float* pa   = (const float*)d_in[9];
    const float* gw   = (const float*)d_in[10];
    const float* gb   = (const float*)d_in[11];
    const float* gms  = (const float*)d_in[12];
    float* out = (float*)d_out;

    int N = in_sizes[0] / IN_C;
    int E = in_sizes[2] / EDIM;
    int total = N * OUT_C;
    int nbN = (N + 255) / 256;
    int nbE = (E + 255) / 256;

    // workspace layout (degcnt first for 8B alignment; rec LAST for fallback)
    char* p = (char*)d_ws;
    u64*   degcnt = (u64*)p;  p += sizeof(u64) * (size_t)N;
    float* dinv   = (float*)p; p += sizeof(float) * (size_t)N;
    __half* xts   = (__half*)p; p += sizeof(__half) * (size_t)N * OUT_C;
    float* sums   = (float*)p; p += sizeof(float) * 128;
    int*   cnt    = (int*)p;   p += sizeof(int) * (size_t)N;
    int*   startv = (int*)p;   p += sizeof(int) * (size_t)N;
    int*   bsums  = (int*)p;   p += sizeof(int) * 1024;
    int2*  tmp    = (int2*)p;  p += sizeof(int2) * (size_t)E;
    int2*  rec    = (int2*)p;  p += sizeof(int2) * (size_t)E;
    size_t need = (size_t)(p - (char*)d_ws);
    bool use_csr = (need <= ws_size) && (nbN <= 1024);

    k_init <<<nbN, 256, 0, stream>>>(degcnt, sums, N);
    k_edge <<<nbE, 256, 0, stream>>>(ea, ei, w1, b1, w2, b2, degcnt, tmp, E);

    if (use_csr) {
        k_scan1 <<<nbN, 256, 0, stream>>>(degcnt, startv, bsums, dinv, cnt, N);
        k_scan2 <<<1, 1024, 0, stream>>>(bsums, nbN);
        k_pass2 <<<nbE, 256, 0, stream>>>(ei, tmp, startv, bsums, rec, E);
        k_xt    <<<(N + 63) / 64, 256, 0, stream>>>(x, lw, dinv, xts, N);
        k_gather<<<(N + 3) / 4, 256, 0, stream>>>(rec, startv, bsums, cnt, dinv, xts, bias, out, N);
    } else {
        k_finish<<<nbN, 256, 0, stream>>>(degcnt, dinv, cnt, N);
        k_xt    <<<(N + 63) / 64, 256, 0, stream>>>(x, lw, dinv, xts, N);
        k_init_out<<<(total + 255) / 256, 256, 0, stream>>>(bias, dinv, xts, out, total);
        long st = (long)E * 64;
        k_scatter <<<(unsigned)((st + 255) / 256), 256, 0, stream>>>(ei, tmp, dinv, xts, out, E);
    }

    k_stats <<<512, 256, 0, stream>>>(out, pa, sums, total);
    k_apply <<<(total + 255) / 256, 256, 0, stream>>>(out, pa, sums, gw, gb, gms, total,
                                                      1.0f / (float)N);
}